// Round 1
// 29304.016 us; speedup vs baseline: 1.0920x; 1.0920x over previous
//
#include <hip/hip_runtime.h>

#define SEQ 32768
#define ISZ 256
#define HSZ 512
#define OSZ 256
#define NLAUNCH 64       // all 64 blocks run the XCD election; 8 winners persist
#define RTHREADS 512     // 8 waves: wave g is "home" (reduce+publish), rest poll
#define SENT 0x7FAAAAAAu // NaN sentinel for the slow (fabric) path
#define KFAST 8          // fast-poll iterations before falling back
#define LATCH_T 48       // fast-path verification window (steps)

typedef unsigned long long u64;
typedef _Float16 half2_t __attribute__((ext_vector_type(2)));

#if defined(__has_builtin)
#if __has_builtin(__builtin_amdgcn_fdot2)
#define HAVE_FDOT2 1
#endif
#endif

__device__ __forceinline__ float dot2f(half2_t a, half2_t b, float c) {
#ifdef HAVE_FDOT2
  return __builtin_amdgcn_fdot2(a, b, c, false);   // v_dot2_f32_f16
#else
  return fmaf((float)a.x, (float)b.x, fmaf((float)a.y, (float)b.y, c));
#endif
}
__device__ __forceinline__ half2_t bch2(unsigned u) {
  return __builtin_bit_cast(half2_t, u);
}
__device__ __forceinline__ unsigned pkrtz_u(float x, float y) {
  return __builtin_bit_cast(unsigned, __builtin_amdgcn_cvt_pkrtz(x, y));
}

// ---------------------------------------------------------------------------
// Generic tiled GEMM:  C[M,N] = A[M,K] @ W[N,K]^T + bias[N]   (unchanged)
// ---------------------------------------------------------------------------
__global__ __launch_bounds__(256) void gemm_bt_bias(
    const float* __restrict__ A, const float* __restrict__ W,
    const float* __restrict__ bias, float* __restrict__ C,
    int M, int N, int K)
{
  __shared__ float As[32][68];
  __shared__ float Bs[32][68];
  const int tx = threadIdx.x;
  const int tn = tx & 15, tm = tx >> 4;
  const int m0 = blockIdx.x * 64, n0 = blockIdx.y * 64;
  const int kl = tx & 31;
  const int rl = tx >> 5;
  float acc[4][4] = {};

  for (int kt = 0; kt < K; kt += 32) {
#pragma unroll
    for (int i = 0; i < 8; ++i) {
      int m = rl + i * 8;
      As[kl][m] = A[(size_t)(m0 + m) * K + kt + kl];
      Bs[kl][m] = W[(size_t)(n0 + m) * K + kt + kl];
    }
    __syncthreads();
#pragma unroll
    for (int k = 0; k < 32; ++k) {
      float a[4], b[4];
#pragma unroll
      for (int i = 0; i < 4; ++i) a[i] = As[k][tm * 4 + i];
#pragma unroll
      for (int j = 0; j < 4; ++j) b[j] = Bs[k][tn * 4 + j];
#pragma unroll
      for (int i = 0; i < 4; ++i)
#pragma unroll
        for (int j = 0; j < 4; ++j)
          acc[i][j] = fmaf(a[i], b[j], acc[i][j]);
    }
    __syncthreads();
  }
#pragma unroll
  for (int i = 0; i < 4; ++i) {
    int m = m0 + tm * 4 + i;
#pragma unroll
    for (int j = 0; j < 4; ++j) {
      int n = n0 + tn * 4 + j;
      C[(size_t)m * N + n] = acc[i][j] + bias[n];
    }
  }
}

// Slow path (r10-proven): 2-deep pipelined sentinel poll, fabric-coherent.
__device__ __forceinline__ float poll_sent(const float* p, unsigned sent) {
  float a, b;
  asm volatile(
      "s_waitcnt vmcnt(0)\n\t"
      "global_load_dword %0, %2, off sc0 sc1\n\t"
      "global_load_dword %1, %2, off sc0 sc1\n"
      "1:\n\t"
      "s_waitcnt vmcnt(1)\n\t"
      "v_cmp_eq_u32 vcc, %3, %0\n\t"
      "s_cbranch_vccz 3f\n\t"
      "global_load_dword %0, %2, off sc0 sc1\n\t"
      "s_waitcnt vmcnt(1)\n\t"
      "v_cmp_eq_u32 vcc, %3, %1\n\t"
      "s_cbranch_vccz 2f\n\t"
      "global_load_dword %1, %2, off sc0 sc1\n\t"
      "s_branch 1b\n"
      "2:\n\t"
      "v_mov_b32 %0, %1\n"
      "3:\n\t"
      "s_waitcnt vmcnt(0)"
      : "=&v"(a), "=&v"(b)
      : "v"(p), "v"(sent)
      : "memory", "vcc");
  return a;
}

// Fast path: sc0-only (L1-bypass, L2-scope). With the runtime election all
// participants are PROVABLY on one XCD, so this is the common case; bounded
// K + sentinel fallback still guarantees correctness regardless.
__device__ __forceinline__ u64 load_fast(const u64* p) {
  u64 v;
  asm volatile("global_load_dwordx2 %0, %1, off sc0\n\t"
               "s_waitcnt vmcnt(0)"
               : "=v"(v) : "v"(p) : "memory");
  return v;
}
__device__ __forceinline__ void store_fast(u64* p, u64 v) {
  asm volatile("global_store_dwordx2 %0, %1, off sc0" :: "v"(p), "v"(v)
               : "memory");
}

// ---------------------------------------------------------------------------
// Persistent recurrence, ROUND-13: runtime XCD election + barrier reduce.
//  (a) ELECTION: blocks read HW_REG_XCC_ID, register device-scope; the 8th
//      registrant on an XCD CASes that XCD as winner -> exactly 8 blocks,
//      provably same-XCD (pigeonhole over 64 blocks / 8 XCDs). Losers exit.
//  (b) Producer wave removed: 8 waves; wave g ("home") keeps chunk g in
//      registers, reduces after ONE __syncthreads/step (double-buffered
//      partials), publishes ring-first then h_hist. Kills the LDS
//      flag-store/spin hop (~250cy) and the hown/hofl hop.
//  (c) tanh tail: v_rcp_f32 + fma instead of IEEE divide.
// Correctness is placement-independent: bounded KFAST + latched fallback to
// the r10 sentinel poll; ring slot reuse at t+4 causally ordered (dense
// coupling bounds inter-block skew to <=1 step).
// ---------------------------------------------------------------------------
__global__ __launch_bounds__(RTHREADS, 2) void rnn_recur(
    const float* __restrict__ P,     // [SEQ][HSZ]
    const float* __restrict__ Wh,    // [HSZ][HSZ]
    float* __restrict__ h_hist,      // [SEQ+1][HSZ]; row0=0, rows 1..=SENT
    u64* __restrict__ fring,         // [8 consumerWG][4 slot][8 chunk][64]
    int* __restrict__ elect)         // [0..7]=per-XCD count, [8]=winner (-1)
{
  const int tid = threadIdx.x;
  const int w = tid >> 6;            // wave 0..7
  const int l = tid & 63;

  __shared__ float part[2][8][64];   // partials, double-buffered by t&1
  __shared__ int s_role;

  // -------- one-time election (tid 0 of every block) --------
  if (tid == 0) {
    unsigned xcc;
    asm volatile("s_getreg_b32 %0, hwreg(HW_REG_XCC_ID)" : "=s"(xcc));
    xcc &= 7u;
    int role = -1;
    int r = __hip_atomic_fetch_add(&elect[xcc], 1, __ATOMIC_RELAXED,
                                   __HIP_MEMORY_SCOPE_AGENT);
    if (r < 8) {
      if (r == 7) {                  // 8th block on this XCD: declare winner
        int exp_ = -1;
        (void)__hip_atomic_compare_exchange_strong(
            &elect[8], &exp_, (int)xcc,
            __ATOMIC_RELEASE, __ATOMIC_RELAXED, __HIP_MEMORY_SCOPE_AGENT);
      }
      int wv;
      do {
        wv = __hip_atomic_load(&elect[8], __ATOMIC_ACQUIRE,
                               __HIP_MEMORY_SCOPE_AGENT);
      } while (wv < 0);              // guaranteed set: pigeonhole 64/8
      if (wv == (int)xcc) role = r;  // ranks 0..7 on winner XCD participate
    }
    s_role = role;
  }
  __syncthreads();
  const int g = s_role;              // participant id 0..7, or -1
  if (g < 0) return;

  const int g64 = g << 6;
  const int row = g64 + l;           // block owns output rows [g64, g64+64)
  const int kbase = w << 6;          // wave owns k-chunk w

  // Lane's 64 weights, f16-packed: 32 half2 regs (r10-proven dot).
  unsigned wreg[32];
  {
    const float2* ws = (const float2*)(Wh + (size_t)row * HSZ + kbase);
#pragma unroll
    for (int j = 0; j < 32; ++j) {
      float2 f = ws[j];
      unsigned u = pkrtz_u(f.x, f.y);
      asm("" : "+v"(u));
      wreg[j] = u;
    }
  }

  const bool home = (w == g);        // home wave: chunk g lives in hreg
  float hreg = 0.f;                  // h[t][row] for home wave (h[0]=0)
  float pv = home ? P[row] : 0.f;    // P[t], prefetched one step ahead
  float pvn = 0.f;
  int fastok = 0, use_fast = 1;

  for (int t = 0; t < SEQ; ++t) {
    float vh = 0.f;
    if (home) {
      vh = hreg;                     // register-local, zero-latency
    } else if (t > 0) {
      int got = 0;
      if (use_fast) {
        const u64* fp = fring + (((size_t)g * 4 + (t & 3)) * 8 + w) * 64 + l;
        for (int k = 0; k < KFAST; ++k) {
          u64 v = load_fast(fp);
          if (__all((int)((unsigned)(v >> 32) == (unsigned)t))) {
            vh = __uint_as_float((unsigned)v);
            got = 1;
            break;
          }
        }
        if (t <= LATCH_T) {
          fastok += got;
          if (t == LATCH_T && fastok < LATCH_T - 8) use_fast = 0;
        }
      }
      if (!got)
        vh = poll_sent(h_hist + (size_t)t * HSZ + kbase + l, SENT);
    }

    // Pack h to f16 pairs; 32 readlane + 32 dot2, 4 accumulator chains.
    float vn = __shfl_xor(vh, 1);
    unsigned hpu = pkrtz_u(vh, vn);
    float a0 = 0.f, a1 = 0.f, a2 = 0.f, a3 = 0.f;
#pragma unroll
    for (int j = 0; j < 8; ++j) {
      a0 = dot2f(bch2(wreg[4 * j + 0]),
                 bch2(__builtin_amdgcn_readlane(hpu, 8 * j + 0)), a0);
      a1 = dot2f(bch2(wreg[4 * j + 1]),
                 bch2(__builtin_amdgcn_readlane(hpu, 8 * j + 2)), a1);
      a2 = dot2f(bch2(wreg[4 * j + 2]),
                 bch2(__builtin_amdgcn_readlane(hpu, 8 * j + 4)), a2);
      a3 = dot2f(bch2(wreg[4 * j + 3]),
                 bch2(__builtin_amdgcn_readlane(hpu, 8 * j + 6)), a3);
    }
    part[t & 1][w][l] = (a0 + a1) + (a2 + a3);

    __syncthreads();                 // ONE barrier/step (part double-buffered)

    if (home) {
      // P prefetch for t+1: issued now, consumed next step (covered by a
      // full step; not in flight across this step's barrier drain).
      pvn = P[(size_t)(t + 1 < SEQ ? t + 1 : SEQ - 1) * HSZ + row];
      const int buf = t & 1;
      float p0 = part[buf][0][l], p1 = part[buf][1][l];
      float p2 = part[buf][2][l], p3 = part[buf][3][l];
      float p4 = part[buf][4][l], p5 = part[buf][5][l];
      float p6 = part[buf][6][l], p7 = part[buf][7][l];
      float s = ((p0 + p1) + (p2 + p3)) + ((p4 + p5) + (p6 + p7));
      float xv = s + pv;
      xv = fminf(fmaxf(xv, -15.f), 15.f);
      float e = __expf(2.f * xv);
      float hn = fmaf(-2.f, __builtin_amdgcn_rcpf(e + 1.f), 1.f); // tanh(xv)
      hreg = hn;
      // Fast publish FIRST (consumer-visible path), tagged {step,val}.
      const u64 pk = ((u64)(unsigned)(t + 1) << 32) | (u64)__float_as_uint(hn);
      const int slot = (t + 1) & 3;
#pragma unroll
      for (int j = 0; j < 8; ++j)
        store_fast(fring + (((size_t)j * 4 + slot) * 8 + g) * 64 + l, pk);
      // Slow-path + final-output publish (fabric; value IS the signal).
      __hip_atomic_store(&h_hist[(size_t)(t + 1) * HSZ + row], hn,
                         __ATOMIC_RELAXED, __HIP_MEMORY_SCOPE_AGENT);
      pv = pvn;
    }
  }
}

// ---------------------------------------------------------------------------
extern "C" void kernel_launch(void* const* d_in, const int* in_sizes, int n_in,
                              void* d_out, int out_size, void* d_ws, size_t ws_size,
                              hipStream_t stream) {
  const float* x  = (const float*)d_in[0];  // [SEQ][ISZ]
  const float* Wx = (const float*)d_in[1];  // [HSZ][ISZ]
  const float* Wh = (const float*)d_in[2];  // [HSZ][HSZ]
  const float* Wy = (const float*)d_in[3];  // [OSZ][HSZ]
  const float* bh = (const float*)d_in[4];  // [HSZ]
  const float* by = (const float*)d_in[5];  // [OSZ]
  float* out = (float*)d_out;               // [SEQ][OSZ]

  float* P      = (float*)d_ws;             // SEQ*HSZ      (64 MB)
  float* h_hist = P + (size_t)SEQ * HSZ;    // (SEQ+1)*HSZ  (64 MB)
  u64*   fring  = (u64*)(h_hist + (size_t)(SEQ + 1) * HSZ); // 128 KB
  int*   elect  = (int*)(fring + (size_t)8 * 4 * 8 * 64);   // 9 ints

  // Sentinel-fill h_hist (slow path), zero row 0; zero fring tags; reset
  // election state (counts=0, winner=-1) every replay.
  (void)hipMemsetD32Async((hipDeviceptr_t)h_hist, (int)SENT,
                          (size_t)(SEQ + 1) * HSZ, stream);
  (void)hipMemsetAsync(h_hist, 0, HSZ * sizeof(float), stream);
  (void)hipMemsetAsync(fring, 0, (size_t)8 * 4 * 8 * 64 * sizeof(u64), stream);
  (void)hipMemsetAsync(elect, 0, 8 * sizeof(int), stream);
  (void)hipMemsetAsync(elect + 8, 0xFF, sizeof(int), stream); // winner = -1

  // Phase 1: P = x @ Wx^T + bh
  gemm_bt_bias<<<dim3(SEQ / 64, HSZ / 64), dim3(256), 0, stream>>>(
      x, Wx, bh, P, SEQ, HSZ, ISZ);

  // Phase 2: recurrence (8 participants, elected same-XCD at runtime)
  rnn_recur<<<dim3(NLAUNCH), dim3(RTHREADS), 0, stream>>>(
      P, Wh, h_hist, fring, elect);

  // Phase 3: y = h_hist[1..] @ Wy^T + by
  gemm_bt_bias<<<dim3(SEQ / 64, OSZ / 64), dim3(256), 0, stream>>>(
      h_hist + HSZ, Wy, by, out, SEQ, OSZ, HSZ);
}